// Round 8
// baseline (185.032 us; speedup 1.0000x reference)
//
#include <hip/hip_runtime.h>

#define BB 4096   // batch
#define TT 512    // time steps
#define DD 32     // input dim
#define NL 10     // layers
#define PH 8      // steps per phase
#define PHASES 66 // 528 steps / 8

static constexpr float L2E = 1.4426950408889634f;   // log2(e)

typedef float f4 __attribute__((ext_vector_type(4)));

__device__ __forceinline__ float fexp2(float x) { return __builtin_amdgcn_exp2f(x); }
__device__ __forceinline__ float frcp(float x)  { return __builtin_amdgcn_rcpf(x); }

// row_shr:1 within each 16-lane row; row-lane 0 gets 0 (bound_ctrl).
__device__ __forceinline__ float dpp_shr1(float x) {
    int r = __builtin_amdgcn_update_dpp(0, __float_as_int(x), 0x111, 0xF, 0xF, true);
    return __int_as_float(r);
}

// ---------------------------------------------------------------------------
// Fused producer-consumer kernel. 1024 blocks x 128 threads (2 waves).
//  wave 1 (producer): computes G0[t] = scale*(W_ih0.x[b,t]+b0) for the
//    block's 4 chains, 8 steps per phase, TWO phases ahead, into LDS.
//    8 lanes cooperate per row (nt loads, shfl_xor butterfly) - R7's
//    proven transform pattern, minus the global G0 round-trip.
//  wave 0 (consumer): R4's skewed pipeline (byte-identical STEP math),
//    4 chains x 16-lane rows, DPP handoff, register ring A/B refilled
//    from LDS one phase ahead. __syncthreads() per phase (67 total).
// No workspace needed: G0 never touches HBM.
// ---------------------------------------------------------------------------
__global__ __launch_bounds__(128) void k_fused(
    const float* __restrict__ x, const float* __restrict__ Wih0,
    const float* __restrict__ Whh0, const float* __restrict__ b0,
    const float* __restrict__ Wihr, const float* __restrict__ Whhr,
    const float* __restrict__ br, float* __restrict__ out)
{
    __shared__ float4 g0lds[4][532];   // [chain-in-block][step]; 532 pad -> 2-way banks

    const int tid  = threadIdx.x;
    const int wave = tid >> 6;
    const int lane = tid & 63;
    const int blk  = blockIdx.x;

    if (wave == 1) {
        // ================= producer =================
        const int g  = lane >> 3;      // step-within-phase 0..7
        const int ch = lane & 7;       // float4 chunk of 32-wide row
        f4 w0 = *(const f4*)(Wih0 + 0 * DD + ch * 4);
        f4 w1 = *(const f4*)(Wih0 + 1 * DD + ch * 4);
        f4 w2 = *(const f4*)(Wih0 + 2 * DD + ch * 4);
        f4 w3 = *(const f4*)(Wih0 + 3 * DD + ch * 4);
        const float b0s = b0[0], b1s = b0[1], b2s = b0[2], b3s = b0[3];

        auto produce = [&](int p) {
            int t = p * PH + g;
            if (t > TT - 1) t = TT - 1;          // steps >= 512: duplicate (discarded)
#pragma unroll
            for (int ci = 0; ci < 4; ci++) {
                const f4* src = (const f4*)(x + ((size_t)(blk * 4 + ci) * TT + t) * DD) + ch;
                f4 v = __builtin_nontemporal_load(src);
                float p0 = v.x * w0.x + v.y * w0.y + v.z * w0.z + v.w * w0.w;
                float p1 = v.x * w1.x + v.y * w1.y + v.z * w1.z + v.w * w1.w;
                float p2 = v.x * w2.x + v.y * w2.y + v.z * w2.z + v.w * w2.w;
                float p3 = v.x * w3.x + v.y * w3.y + v.z * w3.z + v.w * w3.w;
#pragma unroll
                for (int m = 1; m <= 4; m <<= 1) {
                    p0 += __shfl_xor(p0, m);
                    p1 += __shfl_xor(p1, m);
                    p2 += __shfl_xor(p2, m);
                    p3 += __shfl_xor(p3, m);
                }
                if (ch == 0) {
                    float4 o;
                    o.x = -L2E * (p0 + b0s);
                    o.y = -L2E * (p1 + b1s);
                    o.z = -2.f * L2E * (p2 + b2s);
                    o.w = -L2E * (p3 + b3s);
                    g0lds[ci][p * PH + g] = o;
                }
            }
        };

        produce(0);
        produce(1);
        __syncthreads();                          // barrier #0
        for (int p = 0; p < PHASES; p++) {
            if (p + 2 < PHASES) produce(p + 2);
            __syncthreads();                      // barrier #p+1
        }
    } else {
        // ================= consumer (pipe) =================
        const int cidx = lane >> 4;
        const int l = lane & 15;                  // 0..9 live, 10..15 junk
        const int chain = blk * 4 + cidx;

        const float sk0 = -L2E, sk1 = -L2E, sk2 = -2.f * L2E, sk3 = -L2E;
        const bool isl0 = (l == 0), isl9 = (l == NL - 1);
        const int li = (l >= 1 && l <= 9) ? (l - 1) : 0;

        float wi0 = 0, wi1 = 0, wi2 = 0, wi3 = 0;
        float wh0, wh1, wh2, wh3;
        float bb0 = 0, bb1 = 0, bb2 = 0, bb3 = 0;
        if (isl0) {
            wh0 = sk0 * Whh0[0]; wh1 = sk1 * Whh0[1];
            wh2 = sk2 * Whh0[2]; wh3 = sk3 * Whh0[3];
        } else {
            const float* pi = Wihr + li * 4;
            const float* ph = Whhr + li * 4;
            const float* pb = br   + li * 4;
            wi0 = sk0 * pi[0]; wi1 = sk1 * pi[1]; wi2 = sk2 * pi[2]; wi3 = sk3 * pi[3];
            wh0 = sk0 * ph[0]; wh1 = sk1 * ph[1]; wh2 = sk2 * ph[2]; wh3 = sk3 * ph[3];
            bb0 = sk0 * pb[0]; bb1 = sk1 * pb[1]; bb2 = sk2 * pb[2]; bb3 = sk3 * pb[3];
        }

        float* outp = out + (size_t)chain * TT;
        const float c2 = 2.f * L2E;
        float h = 0.f, cs = 0.f;                  // cs = -2*L2E*c
        float o0 = 0.f, o1 = 0.f, o2 = 0.f, o3 = 0.f;

        float4 bbv = make_float4(bb0, bb1, bb2, bb3);
        float4 A[PH], B[PH];
#pragma unroll
        for (int i = 0; i < PH; i++) { A[i] = bbv; B[i] = bbv; }

        auto STEP = [&](float4 g, int s, int jm) {
            int t = s - l;
            bool active = (t >= 0) && (t < TT);

            float hin = dpp_shr1(h);              // h_{l-1}(t)
            float u0 = fmaf(h, wh0, fmaf(hin, wi0, g.x));
            float u1 = fmaf(h, wh1, fmaf(hin, wi1, g.y));
            float u2 = fmaf(h, wh2, fmaf(hin, wi2, g.z));
            float u3 = fmaf(h, wh3, fmaf(hin, wi3, g.w));

            float E0 = fexp2(u0), E1 = fexp2(u1), E2 = fexp2(u2), E3 = fexp2(u3);
            float A0 = 1.f + E0, A1 = 1.f + E1, A2 = 1.f + E2, A3 = 1.f + E3;
            float q02  = frcp(A0 * A2);
            float num2 = fmaf(E2, c2, -c2);
            float term = num2 * q02;
            float r1   = frcp(A1);
            float csn  = fmaf(cs, r1, term);      // -2L2E*c_new
            csn = fminf(fmaxf(csn, -88.f), 88.f);
            float Ec  = fexp2(csn);
            float Ac  = 1.f + Ec;
            float qc3 = frcp(Ac * A3);
            float hn  = (1.f - Ec) * qc3;

            if (active) { cs = csn; h = hn; }

            if (jm == 1) o0 = hn;
            else if (jm == 2) o1 = hn;
            else if (jm == 3) o2 = hn;
            else o3 = hn;                          // jm == 0
            if (jm == 0 && s >= 12 && s <= 520 && isl9) {
                float4 v;
                v.x = 60.f * frcp(1.f + fexp2(-L2E * o0));
                v.y = 60.f * frcp(1.f + fexp2(-L2E * o1));
                v.z = 60.f * frcp(1.f + fexp2(-L2E * o2));
                v.w = 60.f * frcp(1.f + fexp2(-L2E * o3));
                *(float4*)(outp + (s - 12)) = v;
            }
        };

        __syncthreads();                          // barrier #0: ph0, ph1 ready
        if (isl0) {
#pragma unroll
            for (int i = 0; i < PH; i++) A[i] = g0lds[cidx][i];
        }

        for (int pp = 0; pp < PHASES; pp += 2) {
            // phase pp: prefetch B <- ph(pp+1), consume A
            if (isl0) {
#pragma unroll
                for (int i = 0; i < PH; i++) B[i] = g0lds[cidx][(pp + 1) * PH + i];
            }
#pragma unroll
            for (int j = 0; j < PH; j++) STEP(A[j], pp * PH + j, j & 3);
            __syncthreads();
            // phase pp+1: prefetch A <- ph(pp+2), consume B
            if (pp + 2 < PHASES && isl0) {
#pragma unroll
                for (int i = 0; i < PH; i++) A[i] = g0lds[cidx][(pp + 2) * PH + i];
            }
#pragma unroll
            for (int j = 0; j < PH; j++) STEP(B[j], (pp + 1) * PH + j, j & 3);
            __syncthreads();
        }
    }
}

extern "C" void kernel_launch(void* const* d_in, const int* in_sizes, int n_in,
                              void* d_out, int out_size, void* d_ws, size_t ws_size,
                              hipStream_t stream)
{
    const float* x    = (const float*)d_in[0];
    const float* Wih0 = (const float*)d_in[1];
    const float* Whh0 = (const float*)d_in[2];
    const float* b0   = (const float*)d_in[3];
    const float* Wihr = (const float*)d_in[4];
    const float* Whhr = (const float*)d_in[5];
    const float* br   = (const float*)d_in[6];
    float* out = (float*)d_out;

    k_fused<<<BB / 4, 128, 0, stream>>>(x, Wih0, Whh0, b0, Wihr, Whhr, br, out);
}

// Round 9
// 114.948 us; speedup vs baseline: 1.6097x; 1.6097x over previous
//
#include <hip/hip_runtime.h>

#define BB 4096   // batch
#define TT 512    // time steps
#define DD 32     // input dim
#define NL 10     // layers
#define PH 8      // steps per phase
#define PHASES 66 // 528 steps

static constexpr float L2E = 1.4426950408889634f;   // log2(e)

typedef float f4 __attribute__((ext_vector_type(4)));

__device__ __forceinline__ float fexp2(float x) { return __builtin_amdgcn_exp2f(x); }
__device__ __forceinline__ float frcp(float x)  { return __builtin_amdgcn_rcpf(x); }

// row_shr:1 within each 16-lane row; row-lane 0 gets 0 (bound_ctrl).
__device__ __forceinline__ float dpp_shr1(float x) {
    int r = __builtin_amdgcn_update_dpp(0, __float_as_int(x), 0x111, 0xF, 0xF, true);
    return __int_as_float(r);
}

// ---------------------------------------------------------------------------
// Single-wave SIMT-fused kernel. 1024 blocks x 64 threads = 1 wave/SIMD.
// Every lane plays two roles:
//  producer view (pg=lane>>3 step-in-phase, pc=lane&7 chunk): 4 nt x-loads
//    per phase (one per chain), issued TWO phases ahead; dot + 3-round
//    shfl_xor butterfly; pc==0 lanes ds_write G0 into a 2-slot LDS ring.
//  consumer view (cidx=lane>>4 chain, l=lane&15 layer): R4's skewed
//    pipeline, register ring RA/RB refilled from LDS (same wave -> lgkm
//    ordering, NO barriers anywhere).
// G0 never touches HBM; no workspace; no second kernel.
// ---------------------------------------------------------------------------
__global__ __launch_bounds__(64) void k_fused(
    const float* __restrict__ x, const float* __restrict__ Wih0,
    const float* __restrict__ Whh0, const float* __restrict__ b0,
    const float* __restrict__ Wihr, const float* __restrict__ Whhr,
    const float* __restrict__ br, float* __restrict__ out)
{
    __shared__ float4 gbuf[2][4][PH + 1];   // [slot][chain][step], +1 pad de-banks reads

    const int lane = threadIdx.x & 63;
    const int blk  = blockIdx.x;

    // ---- producer-role constants ----
    const int pg = lane >> 3;               // step-in-phase this lane helps produce
    const int pc = lane & 7;                // float4 chunk of the 32-wide x row
    const f4 pw0 = *(const f4*)(Wih0 + 0 * DD + pc * 4);
    const f4 pw1 = *(const f4*)(Wih0 + 1 * DD + pc * 4);
    const f4 pw2 = *(const f4*)(Wih0 + 2 * DD + pc * 4);
    const f4 pw3 = *(const f4*)(Wih0 + 3 * DD + pc * 4);
    const float pb0 = b0[0], pb1 = b0[1], pb2 = b0[2], pb3 = b0[3];

    // ---- consumer-role constants (R4, byte-identical math) ----
    const int cidx = lane >> 4;
    const int l = lane & 15;                // 0..9 live, 10..15 junk (contained)
    const int chain = blk * 4 + cidx;
    const float sk0 = -L2E, sk1 = -L2E, sk2 = -2.f * L2E, sk3 = -L2E;
    const bool isl0 = (l == 0), isl9 = (l == NL - 1);
    const int li = (l >= 1 && l <= 9) ? (l - 1) : 0;

    float wi0 = 0, wi1 = 0, wi2 = 0, wi3 = 0;
    float wh0, wh1, wh2, wh3;
    float bb0 = 0, bb1 = 0, bb2 = 0, bb3 = 0;
    if (isl0) {
        wh0 = sk0 * Whh0[0]; wh1 = sk1 * Whh0[1];
        wh2 = sk2 * Whh0[2]; wh3 = sk3 * Whh0[3];
    } else {
        const float* pi = Wihr + li * 4;
        const float* ph = Whhr + li * 4;
        const float* pb = br   + li * 4;
        wi0 = sk0 * pi[0]; wi1 = sk1 * pi[1]; wi2 = sk2 * pi[2]; wi3 = sk3 * pi[3];
        wh0 = sk0 * ph[0]; wh1 = sk1 * ph[1]; wh2 = sk2 * ph[2]; wh3 = sk3 * ph[3];
        bb0 = sk0 * pb[0]; bb1 = sk1 * pb[1]; bb2 = sk2 * pb[2]; bb3 = sk3 * pb[3];
    }

    float* outp = out + (size_t)chain * TT;
    const float c2 = 2.f * L2E;
    float h = 0.f, cs = 0.f;                // cs = -2*L2E*c
    float o0 = 0.f, o1 = 0.f, o2 = 0.f, o3 = 0.f;

    const float* xb = x + (size_t)blk * 4 * TT * DD;   // + ci*TT*DD + t*DD + pc*4

    f4 VA0, VA1, VA2, VA3, VB0, VB1, VB2, VB3;

    auto LOADV = [&](f4& v0, f4& v1, f4& v2, f4& v3, int p) {
        int t = p * PH + pg; t = t < TT ? t : TT - 1;   // tail clamps (discarded)
        const float* base = xb + (size_t)t * DD + pc * 4;
        v0 = __builtin_nontemporal_load((const f4*)(base + 0 * TT * DD));
        v1 = __builtin_nontemporal_load((const f4*)(base + 1 * TT * DD));
        v2 = __builtin_nontemporal_load((const f4*)(base + 2 * TT * DD));
        v3 = __builtin_nontemporal_load((const f4*)(base + 3 * TT * DD));
    };

    auto PROD1 = [&](const f4 v, int ci, int slot) {    // ci, slot literal at call site
        float p0 = v.x * pw0.x + v.y * pw0.y + v.z * pw0.z + v.w * pw0.w;
        float p1 = v.x * pw1.x + v.y * pw1.y + v.z * pw1.z + v.w * pw1.w;
        float p2 = v.x * pw2.x + v.y * pw2.y + v.z * pw2.z + v.w * pw2.w;
        float p3 = v.x * pw3.x + v.y * pw3.y + v.z * pw3.z + v.w * pw3.w;
#pragma unroll
        for (int m = 1; m <= 4; m <<= 1) {
            p0 += __shfl_xor(p0, m);
            p1 += __shfl_xor(p1, m);
            p2 += __shfl_xor(p2, m);
            p3 += __shfl_xor(p3, m);
        }
        if (pc == 0) {
            float4 o;
            o.x = -L2E * (p0 + pb0);
            o.y = -L2E * (p1 + pb1);
            o.z = -2.f * L2E * (p2 + pb2);
            o.w = -L2E * (p3 + pb3);
            gbuf[slot][ci][pg] = o;
        }
    };

    auto READR = [&](float4* R, int slot) {
        if (isl0) {
#pragma unroll
            for (int j = 0; j < PH; j++) R[j] = gbuf[slot][cidx][j];
        }
    };

    auto STEP = [&](float4 g, int s, int jm) {
        int t = s - l;
        bool active = (t >= 0) && (t < TT);

        float hin = dpp_shr1(h);                      // h_{l-1}(t)
        float u0 = fmaf(h, wh0, fmaf(hin, wi0, g.x));
        float u1 = fmaf(h, wh1, fmaf(hin, wi1, g.y));
        float u2 = fmaf(h, wh2, fmaf(hin, wi2, g.z));
        float u3 = fmaf(h, wh3, fmaf(hin, wi3, g.w));

        float E0 = fexp2(u0), E1 = fexp2(u1), E2 = fexp2(u2), E3 = fexp2(u3);
        float A0 = 1.f + E0, A1 = 1.f + E1, A2 = 1.f + E2, A3 = 1.f + E3;
        float q02  = frcp(A0 * A2);
        float num2 = fmaf(E2, c2, -c2);
        float term = num2 * q02;
        float r1   = frcp(A1);
        float csn  = fmaf(cs, r1, term);              // -2L2E*c_new
        csn = fminf(fmaxf(csn, -88.f), 88.f);
        float Ec  = fexp2(csn);
        float Ac  = 1.f + Ec;
        float qc3 = frcp(Ac * A3);
        float hn  = (1.f - Ec) * qc3;

        if (active) { cs = csn; h = hn; }

        if (jm == 1) o0 = hn;
        else if (jm == 2) o1 = hn;
        else if (jm == 3) o2 = hn;
        else o3 = hn;                                  // jm == 0
        if (jm == 0 && s >= 12 && s <= 520 && isl9) {
            float4 v;
            v.x = 60.f * frcp(1.f + fexp2(-L2E * o0));
            v.y = 60.f * frcp(1.f + fexp2(-L2E * o1));
            v.z = 60.f * frcp(1.f + fexp2(-L2E * o2));
            v.w = 60.f * frcp(1.f + fexp2(-L2E * o3));
            *(float4*)(outp + (s - 12)) = v;
        }
    };

    float4 RA[PH], RB[PH];
    float4 bbv = make_float4(bb0, bb1, bb2, bb3);
#pragma unroll
    for (int i = 0; i < PH; i++) { RA[i] = bbv; RB[i] = bbv; }

    // prologue: VA<-ph0, VB<-ph1; produce ph0; regs<-ph0; VA<-ph2
    LOADV(VA0, VA1, VA2, VA3, 0);
    LOADV(VB0, VB1, VB2, VB3, 1);
    PROD1(VA0, 0, 0); PROD1(VA1, 1, 0); PROD1(VA2, 2, 0); PROD1(VA3, 3, 0);
    READR(RA, 0);
    LOADV(VA0, VA1, VA2, VA3, 2);

    // steady state (2 phases per iteration, all indices static):
    // invariant at top: RA=regs(ph p), VB=x(ph p+1), VA=x(ph p+2)
    for (int p = 0; p < PHASES; p += 2) {
        PROD1(VB0, 0, 1); PROD1(VB1, 1, 1); PROD1(VB2, 2, 1); PROD1(VB3, 3, 1);
#pragma unroll
        for (int j = 0; j < PH; j++) STEP(RA[j], p * PH + j, j & 3);
        READR(RB, 1);                                  // regs <- ph p+1
        LOADV(VB0, VB1, VB2, VB3, p + 3);

        PROD1(VA0, 0, 0); PROD1(VA1, 1, 0); PROD1(VA2, 2, 0); PROD1(VA3, 3, 0);
#pragma unroll
        for (int j = 0; j < PH; j++) STEP(RB[j], (p + 1) * PH + j, j & 3);
        READR(RA, 0);                                  // regs <- ph p+2
        LOADV(VA0, VA1, VA2, VA3, p + 4);
    }
}

extern "C" void kernel_launch(void* const* d_in, const int* in_sizes, int n_in,
                              void* d_out, int out_size, void* d_ws, size_t ws_size,
                              hipStream_t stream)
{
    const float* x    = (const float*)d_in[0];
    const float* Wih0 = (const float*)d_in[1];
    const float* Whh0 = (const float*)d_in[2];
    const float* b0   = (const float*)d_in[3];
    const float* Wihr = (const float*)d_in[4];
    const float* Whhr = (const float*)d_in[5];
    const float* br   = (const float*)d_in[6];
    float* out = (float*)d_out;

    k_fused<<<BB / 4, 64, 0, stream>>>(x, Wih0, Whh0, b0, Wihr, Whhr, br, out);
}

// Round 10
// 91.232 us; speedup vs baseline: 2.0281x; 1.2600x over previous
//
#include <hip/hip_runtime.h>

#define BB 4096   // batch
#define TT 512    // time steps
#define DD 32     // input dim
#define NL 10     // layers
#define PH 8      // steps per phase
#define PHASES 66 // 528 steps

static constexpr float L2E = 1.4426950408889634f;   // log2(e)

typedef float f4 __attribute__((ext_vector_type(4)));

__device__ __forceinline__ float fexp2(float x) { return __builtin_amdgcn_exp2f(x); }
__device__ __forceinline__ float frcp(float x)  { return __builtin_amdgcn_rcpf(x); }
__device__ __forceinline__ float fmed3(float x, float a, float b) {
    return __builtin_amdgcn_fmed3f(x, a, b);
}

// row_shr:1 within each 16-lane row; row-lane 0 gets 0 (bound_ctrl).
__device__ __forceinline__ float dpp_shr1(float x) {
    int r = __builtin_amdgcn_update_dpp(0, __float_as_int(x), 0x111, 0xF, 0xF, true);
    return __int_as_float(r);
}

// x + dpp_perm(x): pure-VALU lane reduction (no LDS, no lgkmcnt).
template<int CTRL>
__device__ __forceinline__ float dpp_add(float x) {
    return x + __int_as_float(__builtin_amdgcn_update_dpp(
        0, __float_as_int(x), CTRL, 0xF, 0xF, true));
}
#define DPP_XOR1 0xB1   // quad_perm [1,0,3,2]
#define DPP_XOR2 0x4E   // quad_perm [2,3,0,1]
#define DPP_ROR4 0x124  // row_ror:4 (valid for lanes r%8==0 cross-quad gather)

// ---------------------------------------------------------------------------
// Single-wave SIMT-fused kernel. 1024 blocks x 64 threads = 1 wave/SIMD.
// R10: producer reduction via DPP (VALU) instead of shfl_xor (ds_bpermute) -
// removes 48 LDS-pipe ops + their lgkmcnt waits per phase, which were
// stalling the serial STEP chain. STEP clamp via v_med3_f32.
// ---------------------------------------------------------------------------
__global__ __launch_bounds__(64) void k_fused(
    const float* __restrict__ x, const float* __restrict__ Wih0,
    const float* __restrict__ Whh0, const float* __restrict__ b0,
    const float* __restrict__ Wihr, const float* __restrict__ Whhr,
    const float* __restrict__ br, float* __restrict__ out)
{
    __shared__ float4 gbuf[2][4][PH + 1];   // [slot][chain][step], +1 pad

    const int lane = threadIdx.x & 63;
    const int blk  = blockIdx.x;

    // ---- producer-role constants ----
    const int pg = lane >> 3;               // step-in-phase this lane helps produce
    const int pc = lane & 7;                // float4 chunk of the 32-wide x row
    const f4 pw0 = *(const f4*)(Wih0 + 0 * DD + pc * 4);
    const f4 pw1 = *(const f4*)(Wih0 + 1 * DD + pc * 4);
    const f4 pw2 = *(const f4*)(Wih0 + 2 * DD + pc * 4);
    const f4 pw3 = *(const f4*)(Wih0 + 3 * DD + pc * 4);
    const float pb0 = b0[0], pb1 = b0[1], pb2 = b0[2], pb3 = b0[3];

    // ---- consumer-role constants (R4, byte-identical math) ----
    const int cidx = lane >> 4;
    const int l = lane & 15;                // 0..9 live, 10..15 junk (contained)
    const int chain = blk * 4 + cidx;
    const float sk0 = -L2E, sk1 = -L2E, sk2 = -2.f * L2E, sk3 = -L2E;
    const bool isl0 = (l == 0), isl9 = (l == NL - 1);
    const int li = (l >= 1 && l <= 9) ? (l - 1) : 0;

    float wi0 = 0, wi1 = 0, wi2 = 0, wi3 = 0;
    float wh0, wh1, wh2, wh3;
    float bb0 = 0, bb1 = 0, bb2 = 0, bb3 = 0;
    if (isl0) {
        wh0 = sk0 * Whh0[0]; wh1 = sk1 * Whh0[1];
        wh2 = sk2 * Whh0[2]; wh3 = sk3 * Whh0[3];
    } else {
        const float* pi = Wihr + li * 4;
        const float* ph = Whhr + li * 4;
        const float* pb = br   + li * 4;
        wi0 = sk0 * pi[0]; wi1 = sk1 * pi[1]; wi2 = sk2 * pi[2]; wi3 = sk3 * pi[3];
        wh0 = sk0 * ph[0]; wh1 = sk1 * ph[1]; wh2 = sk2 * ph[2]; wh3 = sk3 * ph[3];
        bb0 = sk0 * pb[0]; bb1 = sk1 * pb[1]; bb2 = sk2 * pb[2]; bb3 = sk3 * pb[3];
    }

    float* outp = out + (size_t)chain * TT;
    const float c2 = 2.f * L2E;
    float h = 0.f, cs = 0.f;                // cs = -2*L2E*c
    float o0 = 0.f, o1 = 0.f, o2 = 0.f, o3 = 0.f;

    const float* xb = x + (size_t)blk * 4 * TT * DD;

    f4 VA0, VA1, VA2, VA3, VB0, VB1, VB2, VB3;

    auto LOADV = [&](f4& v0, f4& v1, f4& v2, f4& v3, int p) {
        int t = p * PH + pg; t = t < TT ? t : TT - 1;   // tail clamps (discarded)
        const float* base = xb + (size_t)t * DD + pc * 4;
        v0 = __builtin_nontemporal_load((const f4*)(base + 0 * TT * DD));
        v1 = __builtin_nontemporal_load((const f4*)(base + 1 * TT * DD));
        v2 = __builtin_nontemporal_load((const f4*)(base + 2 * TT * DD));
        v3 = __builtin_nontemporal_load((const f4*)(base + 3 * TT * DD));
    };

    auto PROD1 = [&](const f4 v, int ci, int slot) {    // ci, slot literal at call site
        float p0 = v.x * pw0.x + v.y * pw0.y + v.z * pw0.z + v.w * pw0.w;
        float p1 = v.x * pw1.x + v.y * pw1.y + v.z * pw1.z + v.w * pw1.w;
        float p2 = v.x * pw2.x + v.y * pw2.y + v.z * pw2.z + v.w * pw2.w;
        float p3 = v.x * pw3.x + v.y * pw3.y + v.z * pw3.z + v.w * pw3.w;
        // 8-lane sum, pure VALU: pairs, quads, cross-quad (valid on pc==0)
        p0 = dpp_add<DPP_XOR1>(p0); p1 = dpp_add<DPP_XOR1>(p1);
        p2 = dpp_add<DPP_XOR1>(p2); p3 = dpp_add<DPP_XOR1>(p3);
        p0 = dpp_add<DPP_XOR2>(p0); p1 = dpp_add<DPP_XOR2>(p1);
        p2 = dpp_add<DPP_XOR2>(p2); p3 = dpp_add<DPP_XOR2>(p3);
        p0 = dpp_add<DPP_ROR4>(p0); p1 = dpp_add<DPP_ROR4>(p1);
        p2 = dpp_add<DPP_ROR4>(p2); p3 = dpp_add<DPP_ROR4>(p3);
        if (pc == 0) {
            float4 o;
            o.x = -L2E * (p0 + pb0);
            o.y = -L2E * (p1 + pb1);
            o.z = -2.f * L2E * (p2 + pb2);
            o.w = -L2E * (p3 + pb3);
            gbuf[slot][ci][pg] = o;
        }
    };

    auto READR = [&](float4* R, int slot) {
        if (isl0) {
#pragma unroll
            for (int j = 0; j < PH; j++) R[j] = gbuf[slot][cidx][j];
        }
    };

    auto STEP = [&](float4 g, int s, int jm) {
        int t = s - l;
        bool active = (t >= 0) && (t < TT);

        float hin = dpp_shr1(h);                      // h_{l-1}(t)
        float u0 = fmaf(h, wh0, fmaf(hin, wi0, g.x));
        float u1 = fmaf(h, wh1, fmaf(hin, wi1, g.y));
        float u2 = fmaf(h, wh2, fmaf(hin, wi2, g.z));
        float u3 = fmaf(h, wh3, fmaf(hin, wi3, g.w));

        float E0 = fexp2(u0), E1 = fexp2(u1), E2 = fexp2(u2), E3 = fexp2(u3);
        float A0 = 1.f + E0, A1 = 1.f + E1, A2 = 1.f + E2, A3 = 1.f + E3;
        float q02  = frcp(A0 * A2);
        float num2 = fmaf(E2, c2, -c2);
        float term = num2 * q02;
        float r1   = frcp(A1);
        float csn  = fmaf(cs, r1, term);              // -2L2E*c_new
        csn = fmed3(csn, -88.f, 88.f);                // single-op clamp
        float Ec  = fexp2(csn);
        float Ac  = 1.f + Ec;
        float qc3 = frcp(Ac * A3);
        float hn  = (1.f - Ec) * qc3;

        if (active) { cs = csn; h = hn; }

        if (jm == 1) o0 = hn;
        else if (jm == 2) o1 = hn;
        else if (jm == 3) o2 = hn;
        else o3 = hn;                                  // jm == 0
        if (jm == 0 && s >= 12 && s <= 520 && isl9) {
            float4 v;
            v.x = 60.f * frcp(1.f + fexp2(-L2E * o0));
            v.y = 60.f * frcp(1.f + fexp2(-L2E * o1));
            v.z = 60.f * frcp(1.f + fexp2(-L2E * o2));
            v.w = 60.f * frcp(1.f + fexp2(-L2E * o3));
            *(float4*)(outp + (s - 12)) = v;
        }
    };

    float4 RA[PH], RB[PH];
    float4 bbv = make_float4(bb0, bb1, bb2, bb3);
#pragma unroll
    for (int i = 0; i < PH; i++) { RA[i] = bbv; RB[i] = bbv; }

    // prologue: VA<-ph0, VB<-ph1; produce ph0; regs<-ph0; VA<-ph2
    LOADV(VA0, VA1, VA2, VA3, 0);
    LOADV(VB0, VB1, VB2, VB3, 1);
    PROD1(VA0, 0, 0); PROD1(VA1, 1, 0); PROD1(VA2, 2, 0); PROD1(VA3, 3, 0);
    READR(RA, 0);
    LOADV(VA0, VA1, VA2, VA3, 2);

    // steady state: at top RA=regs(ph p), VB=x(ph p+1), VA=x(ph p+2)
    for (int p = 0; p < PHASES; p += 2) {
        PROD1(VB0, 0, 1); PROD1(VB1, 1, 1); PROD1(VB2, 2, 1); PROD1(VB3, 3, 1);
#pragma unroll
        for (int j = 0; j < PH; j++) STEP(RA[j], p * PH + j, j & 3);
        READR(RB, 1);                                  // regs <- ph p+1
        LOADV(VB0, VB1, VB2, VB3, p + 3);

        PROD1(VA0, 0, 0); PROD1(VA1, 1, 0); PROD1(VA2, 2, 0); PROD1(VA3, 3, 0);
#pragma unroll
        for (int j = 0; j < PH; j++) STEP(RB[j], (p + 1) * PH + j, j & 3);
        READR(RA, 0);                                  // regs <- ph p+2
        LOADV(VA0, VA1, VA2, VA3, p + 4);
    }
}

extern "C" void kernel_launch(void* const* d_in, const int* in_sizes, int n_in,
                              void* d_out, int out_size, void* d_ws, size_t ws_size,
                              hipStream_t stream)
{
    const float* x    = (const float*)d_in[0];
    const float* Wih0 = (const float*)d_in[1];
    const float* Whh0 = (const float*)d_in[2];
    const float* b0   = (const float*)d_in[3];
    const float* Wihr = (const float*)d_in[4];
    const float* Whhr = (const float*)d_in[5];
    const float* br   = (const float*)d_in[6];
    float* out = (float*)d_out;

    k_fused<<<BB / 4, 64, 0, stream>>>(x, Wih0, Whh0, b0, Wihr, Whhr, br, out);
}